// Round 1
// baseline (4178.195 us; speedup 1.0000x reference)
//
#include <hip/hip_runtime.h>
#include <cmath>

// FISTA sparse coding, fp32 baseline (round 1: correctness-first).
// N=16384 rows, C=512 channels, D=2048 dict atoms, 5 steps.
// 10 GEMMs of 34.36 GFLOP each, all epilogue-fused.

#define BM 128
#define BN 128
#define BK 16
#define TM 8
#define TN 8
#define LDSP 132   // LDS leading dim (pad 128 -> 132)

constexpr float S_STEP = 0.1f;   // step size
constexpr float LAM    = 0.01f;  // lmbd * step (mu = 0 -> s_mu = 1)

// ---------------------------------------------------------------------------
// gemm_nt: Out[m,n] = epi( sum_k A[m,k] * B[n,k] )   (A:[M,K] rm, B:[Nn,K] rm)
//   EPI 0: Out = max(S*acc - LAM, 0)                          (iter 0)
//   EPI 1: Out = max(coefA*Cc + coefB*Cpre + S*acc - LAM, 0)  (iters 1..3)
//   EPI 2: EPI 1 + accumulate 0.1*sum(c) into loss            (iter 4)
// Note: Out may alias Cpre (in-place generation overwrite) -> no __restrict__
// on Cc/Cpre/Out. Per-element read-before-write within one thread only.
// ---------------------------------------------------------------------------
template<int EPI>
__global__ __launch_bounds__(256)
void gemm_nt_k(const float* __restrict__ A, const float* __restrict__ B,
               int M, int Nn, int K,
               const float* Cc, const float* Cpre, float* Out,
               float coefA, float coefB, float* loss)
{
    __shared__ float As[BK][LDSP];
    __shared__ float Bs[BK][LDSP];

    const int tid = threadIdx.x;
    const int tx  = tid & 15;    // n dir (8 cols each)
    const int ty  = tid >> 4;    // m dir (8 rows each)
    const int rowBase = blockIdx.y * BM;
    const int colBase = blockIdx.x * BN;

    float acc[TM][TN] = {};

    // tile = 128 rows x 16 k = 512 float4 slots; 2 slots/thread
    const int s0  = tid * 2;
    const int r0  = s0 >> 2,       k0o = (s0 & 3) << 2;
    const int r1  = (s0 + 1) >> 2, k1o = ((s0 + 1) & 3) << 2;

    const float* Ar0 = A + (size_t)(rowBase + r0) * K + k0o;
    const float* Ar1 = A + (size_t)(rowBase + r1) * K + k1o;
    const float* Br0 = B + (size_t)(colBase + r0) * K + k0o;
    const float* Br1 = B + (size_t)(colBase + r1) * K + k1o;

    for (int kb = 0; kb < K; kb += BK) {
        float4 a0 = *(const float4*)(Ar0 + kb);
        float4 a1 = *(const float4*)(Ar1 + kb);
        float4 b0 = *(const float4*)(Br0 + kb);
        float4 b1 = *(const float4*)(Br1 + kb);
        __syncthreads();
        As[k0o+0][r0] = a0.x; As[k0o+1][r0] = a0.y; As[k0o+2][r0] = a0.z; As[k0o+3][r0] = a0.w;
        As[k1o+0][r1] = a1.x; As[k1o+1][r1] = a1.y; As[k1o+2][r1] = a1.z; As[k1o+3][r1] = a1.w;
        Bs[k0o+0][r0] = b0.x; Bs[k0o+1][r0] = b0.y; Bs[k0o+2][r0] = b0.z; Bs[k0o+3][r0] = b0.w;
        Bs[k1o+0][r1] = b1.x; Bs[k1o+1][r1] = b1.y; Bs[k1o+2][r1] = b1.z; Bs[k1o+3][r1] = b1.w;
        __syncthreads();
        #pragma unroll
        for (int kk = 0; kk < BK; ++kk) {
            float a[TM], b[TN];
            *(float4*)&a[0] = *(const float4*)&As[kk][ty*TM];
            *(float4*)&a[4] = *(const float4*)&As[kk][ty*TM+4];
            *(float4*)&b[0] = *(const float4*)&Bs[kk][tx*TN];
            *(float4*)&b[4] = *(const float4*)&Bs[kk][tx*TN+4];
            #pragma unroll
            for (int i = 0; i < TM; ++i)
                #pragma unroll
                for (int j = 0; j < TN; ++j)
                    acc[i][j] = fmaf(a[i], b[j], acc[i][j]);
        }
    }

    float lsum = 0.f;
    #pragma unroll
    for (int i = 0; i < TM; ++i) {
        const size_t base = (size_t)(rowBase + ty*TM + i) * Nn + colBase + tx*TN;
        #pragma unroll
        for (int jq = 0; jq < TN; jq += 4) {
            float4 v;
            if constexpr (EPI == 0) {
                v.x = fmaxf(S_STEP*acc[i][jq+0] - LAM, 0.f);
                v.y = fmaxf(S_STEP*acc[i][jq+1] - LAM, 0.f);
                v.z = fmaxf(S_STEP*acc[i][jq+2] - LAM, 0.f);
                v.w = fmaxf(S_STEP*acc[i][jq+3] - LAM, 0.f);
            } else {
                const float4 cv = *(const float4*)(Cc   + base + jq);
                const float4 cp = *(const float4*)(Cpre + base + jq);
                v.x = fmaxf(coefA*cv.x + coefB*cp.x + S_STEP*acc[i][jq+0] - LAM, 0.f);
                v.y = fmaxf(coefA*cv.y + coefB*cp.y + S_STEP*acc[i][jq+1] - LAM, 0.f);
                v.z = fmaxf(coefA*cv.z + coefB*cp.z + S_STEP*acc[i][jq+2] - LAM, 0.f);
                v.w = fmaxf(coefA*cv.w + coefB*cp.w + S_STEP*acc[i][jq+3] - LAM, 0.f);
            }
            *(float4*)(Out + base + jq) = v;
            if constexpr (EPI == 2) lsum += v.x + v.y + v.z + v.w;  // c >= 0
        }
    }

    if constexpr (EPI == 2) {
        #pragma unroll
        for (int off = 32; off > 0; off >>= 1) lsum += __shfl_down(lsum, off, 64);
        __shared__ float red[4];
        if ((tid & 63) == 0) red[tid >> 6] = lsum;
        __syncthreads();
        if (tid == 0) atomicAdd(loss, 0.1f * (red[0] + red[1] + red[2] + red[3]));
    }
}

// ---------------------------------------------------------------------------
// gemm_nn: epi( sum_k A[m,k] * B[k,n] )   (A:[M,K] rm, B:[K,Nn] rm)
//   EPI 10: Out  = X - acc                       (residual r)
//   EPI 11: Out  = acc (xp); Out2 = X - acc (r); loss += sum(r*r)
// ---------------------------------------------------------------------------
template<int EPI>
__global__ __launch_bounds__(256)
void gemm_nn_k(const float* __restrict__ A, const float* __restrict__ B,
               int M, int Nn, int K,
               const float* __restrict__ X,
               float* __restrict__ Out, float* __restrict__ Out2, float* loss)
{
    __shared__ float As[BK][LDSP];
    __shared__ float Bs[BK][LDSP];

    const int tid = threadIdx.x;
    const int tx  = tid & 15;
    const int ty  = tid >> 4;
    const int rowBase = blockIdx.y * BM;
    const int colBase = blockIdx.x * BN;

    float acc[TM][TN] = {};

    const int s0  = tid * 2;
    // A tile: 128 rows x 16 k
    const int ar0 = s0 >> 2,       ak0 = (s0 & 3) << 2;
    const int ar1 = (s0 + 1) >> 2, ak1 = ((s0 + 1) & 3) << 2;
    // B tile: 16 k x 128 n (natural layout)
    const int bk0 = s0 >> 5,       bc0 = (s0 & 31) << 2;
    const int bk1 = (s0 + 1) >> 5, bc1 = ((s0 + 1) & 31) << 2;

    const float* Ar0 = A + (size_t)(rowBase + ar0) * K + ak0;
    const float* Ar1 = A + (size_t)(rowBase + ar1) * K + ak1;
    const float* Br0 = B + (size_t)bk0 * Nn + colBase + bc0;
    const float* Br1 = B + (size_t)bk1 * Nn + colBase + bc1;

    for (int kb = 0; kb < K; kb += BK) {
        float4 a0 = *(const float4*)(Ar0 + kb);
        float4 a1 = *(const float4*)(Ar1 + kb);
        float4 b0 = *(const float4*)(Br0 + (size_t)kb * Nn);
        float4 b1 = *(const float4*)(Br1 + (size_t)kb * Nn);
        __syncthreads();
        As[ak0+0][ar0] = a0.x; As[ak0+1][ar0] = a0.y; As[ak0+2][ar0] = a0.z; As[ak0+3][ar0] = a0.w;
        As[ak1+0][ar1] = a1.x; As[ak1+1][ar1] = a1.y; As[ak1+2][ar1] = a1.z; As[ak1+3][ar1] = a1.w;
        *(float4*)&Bs[bk0][bc0] = b0;
        *(float4*)&Bs[bk1][bc1] = b1;
        __syncthreads();
        #pragma unroll
        for (int kk = 0; kk < BK; ++kk) {
            float a[TM], b[TN];
            *(float4*)&a[0] = *(const float4*)&As[kk][ty*TM];
            *(float4*)&a[4] = *(const float4*)&As[kk][ty*TM+4];
            *(float4*)&b[0] = *(const float4*)&Bs[kk][tx*TN];
            *(float4*)&b[4] = *(const float4*)&Bs[kk][tx*TN+4];
            #pragma unroll
            for (int i = 0; i < TM; ++i)
                #pragma unroll
                for (int j = 0; j < TN; ++j)
                    acc[i][j] = fmaf(a[i], b[j], acc[i][j]);
        }
    }

    float lsum = 0.f;
    #pragma unroll
    for (int i = 0; i < TM; ++i) {
        const size_t base = (size_t)(rowBase + ty*TM + i) * Nn + colBase + tx*TN;
        #pragma unroll
        for (int jq = 0; jq < TN; jq += 4) {
            const float4 xv = *(const float4*)(X + base + jq);
            if constexpr (EPI == 10) {
                float4 v;
                v.x = xv.x - acc[i][jq+0];
                v.y = xv.y - acc[i][jq+1];
                v.z = xv.z - acc[i][jq+2];
                v.w = xv.w - acc[i][jq+3];
                *(float4*)(Out + base + jq) = v;
            } else {  // EPI 11
                float4 xp, rv;
                xp.x = acc[i][jq+0]; xp.y = acc[i][jq+1];
                xp.z = acc[i][jq+2]; xp.w = acc[i][jq+3];
                rv.x = xv.x - xp.x; rv.y = xv.y - xp.y;
                rv.z = xv.z - xp.z; rv.w = xv.w - xp.w;
                *(float4*)(Out  + base + jq) = xp;
                *(float4*)(Out2 + base + jq) = rv;
                lsum += rv.x*rv.x + rv.y*rv.y + rv.z*rv.z + rv.w*rv.w;
            }
        }
    }

    if constexpr (EPI == 11) {
        #pragma unroll
        for (int off = 32; off > 0; off >>= 1) lsum += __shfl_down(lsum, off, 64);
        __shared__ float red[4];
        if ((tid & 63) == 0) red[tid >> 6] = lsum;
        __syncthreads();
        if (tid == 0) atomicAdd(loss, red[0] + red[1] + red[2] + red[3]);
    }
}

// ---------------------------------------------------------------------------
extern "C" void kernel_launch(void* const* d_in, const int* in_sizes, int n_in,
                              void* d_out, int out_size, void* d_ws, size_t ws_size,
                              hipStream_t stream)
{
    (void)in_sizes; (void)n_in; (void)out_size; (void)ws_size;

    constexpr int N = 16384, C = 512, D = 2048;
    constexpr size_t ND = (size_t)N * D;   // 33554432
    constexpr size_t NC = (size_t)N * C;   //  8388608

    const float* x = (const float*)d_in[0];   // [N, C]
    const float* W = (const float*)d_in[1];   // [D, C]

    float* out    = (float*)d_out;
    float* c_out  = out;                      // output 0: c  [N, D]
    float* xp_out = out + ND;                 // output 1: xp [N, C]
    float* r_out  = out + ND + NC;            // output 2: r  [N, C]
    float* rloss  = out + ND + 2 * NC;        // output 3
    float* closs  = rloss + 1;                // output 4

    // ws: one odd-generation c buffer (needs ND*4 = 128 MiB)
    float* c_odd  = (float*)d_ws;
    // r scratch reuses the xp region (only written by the final GEMM)
    float* r_ws   = xp_out;

    // zero the two loss accumulators (capture-safe memset node)
    hipMemsetAsync((void*)rloss, 0, 2 * sizeof(float), stream);

    // momentum coefficients, host-computed in double like the reference
    double tp = (std::sqrt(5.0) + 1.0) / 2.0;
    float cfA[5] = {0.f, 1.f, 0.f, 0.f, 0.f};
    float cfB[5] = {0.f, 0.f, 0.f, 0.f, 0.f};
    for (int i = 2; i < 5; ++i) {
        double t = (std::sqrt(1.0 + 4.0 * tp * tp) + 1.0) / 2.0;
        cfA[i] = (float)((tp + t - 1.0) / t);
        cfB[i] = (float)((1.0 - tp) / t);
        tp = t;
    }

    const dim3 blk(256);
    const dim3 gridD(D / BN, N / BM);   // 16 x 128 = 2048 blocks
    const dim3 gridC(C / BN, N / BM);   //  4 x 128 =  512 blocks

    // generation g lives in bufs[g & 1]; c4 must land in c_out -> even = c_out
    float* bufs[2] = {c_out, c_odd};

    // iter 0: c0 = max(s*(x@W^T) - lam, 0)
    gemm_nt_k<0><<<gridD, blk, 0, stream>>>(x, W, N, D, C,
                                            nullptr, nullptr, bufs[0],
                                            0.f, 0.f, nullptr);

    // iters 1..4
    for (int i = 1; i < 5; ++i) {
        const float* cprev = bufs[(i - 1) & 1];  // c_{i-1}
        float*       cnew  = bufs[i & 1];        // holds c_{i-2}; becomes c_i
        // r = x - c_{i-1} @ W
        gemm_nn_k<10><<<gridC, blk, 0, stream>>>(cprev, W, N, C, D,
                                                 x, r_ws, nullptr, nullptr);
        // c_i = max(cfA*c_{i-1} + cfB*c_{i-2} + s*(r@W^T) - lam, 0)
        if (i < 4)
            gemm_nt_k<1><<<gridD, blk, 0, stream>>>(r_ws, W, N, D, C,
                                                    cprev, cnew, cnew,
                                                    cfA[i], cfB[i], nullptr);
        else
            gemm_nt_k<2><<<gridD, blk, 0, stream>>>(r_ws, W, N, D, C,
                                                    cprev, cnew, cnew,
                                                    cfA[i], cfB[i], closs);
    }

    // final: xp = c4 @ W; r = x - xp; r_loss = sum(r*r)
    gemm_nn_k<11><<<gridC, blk, 0, stream>>>(bufs[0], W, N, C, D,
                                             x, xp_out, r_out, rloss);
}

// Round 2
// 1057.619 us; speedup vs baseline: 3.9506x; 3.9506x over previous
//
#include <hip/hip_runtime.h>
#include <cmath>

// FISTA sparse coding, bf16-MFMA version (round 2).
// N=16384 rows, C=512 channels, D=2048 dict atoms, 5 steps.
// All 10 GEMMs as 128x128-tile bf16 MFMA (16x16x32), fp32 accumulate.
// m97-style staging: global_load_lds dwordx4, BK=32, 4 waves x 4x4 tiles.

typedef __attribute__((ext_vector_type(8))) short bf16x8;   // 8 bf16 (4 VGPRs)
typedef __attribute__((ext_vector_type(4))) float f32x4;    // 4 fp32 acc

constexpr float S_STEP = 0.1f;   // step size
constexpr float LAM    = 0.01f;  // lmbd * step (mu=0 -> s_mu=1)

__device__ __forceinline__ unsigned short f2bf(float f) {   // RNE fp32->bf16
    unsigned u = __float_as_uint(f);
    u += 0x7FFFu + ((u >> 16) & 1u);
    return (unsigned short)(u >> 16);
}
__device__ __forceinline__ float bf2f(unsigned short s) {
    return __uint_as_float(((unsigned)s) << 16);
}

__device__ __forceinline__ void async16(const void* g, void* l) {
    // 16B/lane global->LDS DMA; LDS dest = wave-uniform base + lane*16
    __builtin_amdgcn_global_load_lds(
        (const __attribute__((address_space(1))) void*)g,
        (__attribute__((address_space(3))) void*)l, 16, 0, 0);
}

// ---------------------------------------------------------------------------
// gemm_bt<EPI>: acc[m,n] = sum_k A[m,k]*B[n,k]; A:[M,K] bf16 rm, B:[Nn,K] bf16 rm.
//   EPI 0: OutB = bf16(relu(S*acc - LAM))                          (c0)
//   EPI 1: OutB = bf16(relu(cfA*Cc + cfB*Cpre + S*acc - LAM))      (c1..c3)
//   EPI 2: EPI1 + Out32 = v (fp32 c) + closs += 0.1*sum(v)         (c4)
//   EPI 3: OutB = bf16(X32 - acc)                                  (r intermediate)
//   EPI 4: Out32 = acc                                             (xp)
// OutB may alias Cpre (in-place generation overwrite): no restrict on those.
// ---------------------------------------------------------------------------
template<int EPI>
__global__ __launch_bounds__(256)
void gemm_bt(const short* __restrict__ A, const short* __restrict__ B,
             int K, int Nn,
             const unsigned short* Cc, const unsigned short* Cpre,
             const float* __restrict__ X32,
             unsigned short* OutB, float* Out32,
             float cfA, float cfB, float* loss)
{
    __shared__ __align__(16) short As[128 * 32];
    __shared__ __align__(16) short Bs[128 * 32];

    const int tid  = threadIdx.x;
    const int wave = tid >> 6;
    const int lane = tid & 63;
    const int rowBase = blockIdx.y * 128;
    const int colBase = blockIdx.x * 128;

    // staging map: each instr covers 16 rows x 32 k (1024B); lane L -> row L/4, k-chunk (L%4)*8
    const int sRow = lane >> 2;
    const int sK   = (lane & 3) << 3;
    const short* gA = A + (size_t)(rowBase + wave * 32 + sRow) * K + sK;
    const short* gB = B + (size_t)(colBase + wave * 32 + sRow) * K + sK;
    short* lA0 = &As[(wave * 32) * 32];
    short* lA1 = &As[(wave * 32 + 16) * 32];
    short* lB0 = &Bs[(wave * 32) * 32];
    short* lB1 = &Bs[(wave * 32 + 16) * 32];
    const size_t rstep = (size_t)16 * K;

    const int m16  = lane & 15;
    const int quad = lane >> 4;
    const short* paBase = &As[((wave & 1) * 64 + m16) * 32 + quad * 8];
    const short* pbBase = &Bs[((wave >> 1) * 64 + m16) * 32 + quad * 8];

    f32x4 acc[4][4] = {};

    for (int kb = 0; kb < K; kb += 32) {
        __syncthreads();                       // prev iter's ds_reads done
        async16(gA + kb,         lA0);
        async16(gA + kb + rstep, lA1);
        async16(gB + kb,         lB0);
        async16(gB + kb + rstep, lB1);
        __syncthreads();                       // drains vmcnt before barrier
        bf16x8 af[4], bfr[4];
        #pragma unroll
        for (int i = 0; i < 4; ++i) af[i]  = *(const bf16x8*)(paBase + i * 512);
        #pragma unroll
        for (int j = 0; j < 4; ++j) bfr[j] = *(const bf16x8*)(pbBase + j * 512);
        #pragma unroll
        for (int i = 0; i < 4; ++i)
            #pragma unroll
            for (int j = 0; j < 4; ++j)
                acc[i][j] = __builtin_amdgcn_mfma_f32_16x16x32_bf16(
                                af[i], bfr[j], acc[i][j], 0, 0, 0);
    }

    // C/D layout: col = lane&15, row = quad*4 + reg  [m89/m91-verified]
    const int orow = rowBase + (wave & 1) * 64 + quad * 4;
    const int ocol = colBase + (wave >> 1) * 64 + m16;
    float lsum = 0.f;
    #pragma unroll
    for (int i = 0; i < 4; ++i) {
        #pragma unroll
        for (int r = 0; r < 4; ++r) {
            const size_t rowoff = (size_t)(orow + i * 16 + r) * Nn;
            #pragma unroll
            for (int j = 0; j < 4; ++j) {
                const size_t idx = rowoff + ocol + j * 16;
                const float a = acc[i][j][r];
                if constexpr (EPI == 0) {
                    OutB[idx] = f2bf(fmaxf(S_STEP * a - LAM, 0.f));
                } else if constexpr (EPI == 1 || EPI == 2) {
                    float v = fmaxf(cfA * bf2f(Cc[idx]) + cfB * bf2f(Cpre[idx])
                                    + S_STEP * a - LAM, 0.f);
                    OutB[idx] = f2bf(v);
                    if constexpr (EPI == 2) { Out32[idx] = v; lsum += v; }
                } else if constexpr (EPI == 3) {
                    OutB[idx] = f2bf(X32[idx] - a);
                } else {  // EPI 4
                    Out32[idx] = a;
                }
            }
        }
    }

    if constexpr (EPI == 2) {
        #pragma unroll
        for (int off = 32; off; off >>= 1) lsum += __shfl_down(lsum, off, 64);
        if (lane == 0) atomicAdd(loss, 0.1f * lsum);
    }
}

// ---------------------------------------------------------------------------
// prep: W [2048,512] fp32 -> Wb bf16 (same layout) + Wtb bf16 [512,2048]
// ---------------------------------------------------------------------------
__global__ __launch_bounds__(256)
void cvt_w_k(const float* __restrict__ W,
             unsigned short* __restrict__ Wb, unsigned short* __restrict__ Wtb)
{
    __shared__ unsigned short T[64][65];
    const int dBase = blockIdx.y * 64;          // over D=2048
    const int cBase = blockIdx.x * 64;          // over C=512
    const int lc = threadIdx.x & 63;
    const int lr = threadIdx.x >> 6;            // 4 rows per pass
    #pragma unroll
    for (int p = 0; p < 16; ++p) {
        const int dl = p * 4 + lr;
        const size_t idx = (size_t)(dBase + dl) * 512 + cBase + lc;
        const unsigned short b = f2bf(W[idx]);
        Wb[idx] = b;
        T[dl][lc] = b;
    }
    __syncthreads();
    #pragma unroll
    for (int p = 0; p < 16; ++p) {
        const int cl = p * 4 + lr;
        Wtb[(size_t)(cBase + cl) * 2048 + dBase + lc] = T[lc][cl];
    }
}

__global__ __launch_bounds__(256)
void cvt_x_k(const float4* __restrict__ x4, ushort4* __restrict__ xb4, int n4)
{
    for (int i = blockIdx.x * 256 + threadIdx.x; i < n4; i += gridDim.x * 256) {
        const float4 v = x4[i];
        xb4[i] = make_ushort4(f2bf(v.x), f2bf(v.y), f2bf(v.z), f2bf(v.w));
    }
}

// r = x - xp (fp32), rloss += sum(r*r)
__global__ __launch_bounds__(256)
void finalize_k(const float4* __restrict__ x4, const float4* __restrict__ xp4,
                float4* __restrict__ r4, float* __restrict__ rloss, int n4)
{
    float lsum = 0.f;
    for (int i = blockIdx.x * 256 + threadIdx.x; i < n4; i += gridDim.x * 256) {
        const float4 xv = x4[i], pv = xp4[i];
        float4 rv;
        rv.x = xv.x - pv.x; rv.y = xv.y - pv.y;
        rv.z = xv.z - pv.z; rv.w = xv.w - pv.w;
        r4[i] = rv;
        lsum += rv.x * rv.x + rv.y * rv.y + rv.z * rv.z + rv.w * rv.w;
    }
    #pragma unroll
    for (int off = 32; off; off >>= 1) lsum += __shfl_down(lsum, off, 64);
    if ((threadIdx.x & 63) == 0) atomicAdd(rloss, lsum);
}

// ---------------------------------------------------------------------------
extern "C" void kernel_launch(void* const* d_in, const int* in_sizes, int n_in,
                              void* d_out, int out_size, void* d_ws, size_t ws_size,
                              hipStream_t stream)
{
    (void)in_sizes; (void)n_in; (void)out_size; (void)ws_size;

    constexpr int N = 16384, C = 512, D = 2048;
    constexpr size_t ND = (size_t)N * D;
    constexpr size_t NC = (size_t)N * C;

    const float* x = (const float*)d_in[0];   // [N, C]
    const float* W = (const float*)d_in[1];   // [D, C]

    float* out    = (float*)d_out;
    float* c_out  = out;                      // c  [N, D] fp32
    float* xp_out = out + ND;                 // xp [N, C] fp32
    float* r_out  = out + ND + NC;            // r  [N, C] fp32
    float* rloss  = out + ND + 2 * NC;
    float* closs  = rloss + 1;

    // ws: two bf16 c generations (64 MiB each = 128 MiB, round-1-proven size)
    short* cb0 = (short*)d_ws;
    short* cb1 = cb0 + ND;

    // scratch carved from dead phases of d_out:
    // xp region: rb (16MB) + Wb (2MB)  — both dead before final xp write
    // r  region: Wtb (2MB) + xb (16MB) — Wtb read by final gemm, then finalize_k
    //            overwrites the whole r region afterwards
    unsigned short* rb  = (unsigned short*)xp_out;            // [N,C] bf16
    unsigned short* Wb  = (unsigned short*)xp_out + NC;       // [D,C] bf16
    unsigned short* Wtb = (unsigned short*)r_out;             // [C,D] bf16
    unsigned short* xb  = (unsigned short*)r_out + (size_t)D * C;  // [N,C] bf16

    hipMemsetAsync((void*)rloss, 0, 2 * sizeof(float), stream);

    // momentum coefficients (host, double precision like the reference)
    double tp = (std::sqrt(5.0) + 1.0) / 2.0;
    float cfA[5] = {0.f, 1.f, 0.f, 0.f, 0.f};
    float cfB[5] = {0.f, 0.f, 0.f, 0.f, 0.f};
    for (int i = 2; i < 5; ++i) {
        double t = (std::sqrt(1.0 + 4.0 * tp * tp) + 1.0) / 2.0;
        cfA[i] = (float)((tp + t - 1.0) / t);
        cfB[i] = (float)((1.0 - tp) / t);
        tp = t;
    }

    const dim3 blk(256);
    cvt_w_k<<<dim3(C / 64, D / 64), blk, 0, stream>>>(W, Wb, Wtb);
    cvt_x_k<<<dim3(1024), blk, 0, stream>>>((const float4*)x, (ushort4*)xb,
                                            (int)(NC / 4));

    const dim3 gridD(D / 128, N / 128);   // 16 x 128
    const dim3 gridC(C / 128, N / 128);   //  4 x 128

    // c0 = relu(S*(x@W^T) - LAM)
    gemm_bt<0><<<gridD, blk, 0, stream>>>((const short*)xb, (const short*)Wb,
                                          C, D, nullptr, nullptr, nullptr,
                                          (unsigned short*)cb0, nullptr,
                                          0.f, 0.f, nullptr);

    short* bufs[2] = {cb0, cb1};
    for (int i = 1; i < 5; ++i) {
        const short* cprev = bufs[(i - 1) & 1];   // c_{i-1}
        short*       cnew  = bufs[i & 1];         // c_{i-2} -> c_i (in place)
        const unsigned short* cpre2 =
            (i == 1) ? (const unsigned short*)cprev : (const unsigned short*)cnew;
        // r_{i-1} = x - c_{i-1} @ W   (bf16, via Wt)
        gemm_bt<3><<<gridC, blk, 0, stream>>>(cprev, (const short*)Wtb,
                                              D, C, nullptr, nullptr, x,
                                              rb, nullptr, 0.f, 0.f, nullptr);
        // c_i = relu(cfA*c_{i-1} + cfB*c_{i-2} + S*(r@W^T) - LAM)
        if (i < 4)
            gemm_bt<1><<<gridD, blk, 0, stream>>>((const short*)rb, (const short*)Wb,
                                                  C, D, (const unsigned short*)cprev,
                                                  cpre2, nullptr,
                                                  (unsigned short*)cnew, nullptr,
                                                  cfA[i], cfB[i], nullptr);
        else
            gemm_bt<2><<<gridD, blk, 0, stream>>>((const short*)rb, (const short*)Wb,
                                                  C, D, (const unsigned short*)cprev,
                                                  cpre2, nullptr,
                                                  (unsigned short*)cnew, c_out,
                                                  cfA[i], cfB[i], closs);
    }

    // xp = c4 @ W (fp32 out; overwrites rb/Wb which are now dead)
    gemm_bt<4><<<gridC, blk, 0, stream>>>(cb0, (const short*)Wtb,
                                          D, C, nullptr, nullptr, nullptr,
                                          nullptr, xp_out, 0.f, 0.f, nullptr);

    // r = x - xp, rloss = sum(r*r) (overwrites Wtb/xb, now dead)
    finalize_k<<<dim3(1024), blk, 0, stream>>>((const float4*)x,
                                               (const float4*)xp_out,
                                               (float4*)r_out, rloss,
                                               (int)(NC / 4));
}

// Round 3
// 914.382 us; speedup vs baseline: 4.5694x; 1.1566x over previous
//
#include <hip/hip_runtime.h>
#include <cmath>

// FISTA sparse coding, bf16-MFMA + coalesced LDS-bounce epilogues (round 3).
// N=16384, C=512, D=2048, 5 steps. 10 GEMMs, 128x128 tile, 16x16x32 bf16 MFMA.

typedef __attribute__((ext_vector_type(8))) short bf16x8;          // 4 VGPRs
typedef __attribute__((ext_vector_type(8))) unsigned short u16x8;  // 16 B
typedef __attribute__((ext_vector_type(4))) float f32x4;

constexpr float S_STEP = 0.1f;   // step size
constexpr float LAM    = 0.01f;  // lmbd * step (mu=0 -> s_mu=1)

__device__ __forceinline__ unsigned short f2bf(float f) {   // RNE fp32->bf16
    unsigned u = __float_as_uint(f);
    u += 0x7FFFu + ((u >> 16) & 1u);
    return (unsigned short)(u >> 16);
}
__device__ __forceinline__ float bf2f(unsigned short s) {
    return __uint_as_float(((unsigned)s) << 16);
}

__device__ __forceinline__ void async16(const void* g, void* l) {
    __builtin_amdgcn_global_load_lds(
        (const __attribute__((address_space(1))) void*)g,
        (__attribute__((address_space(3))) void*)l, 16, 0, 0);
}

// ---------------------------------------------------------------------------
// gemm_bt<EPI>: acc[m,n] = sum_k A[m,k]*B[n,k]; A:[M,K] bf16 rm, B:[Nn,K] bf16 rm.
//   EPI 0: OutB = bf16(relu(S*acc - LAM))                          (c0)
//   EPI 1: OutB = bf16(relu(cfA*Cc + cfB*Cpre + S*acc - LAM))      (c1..c3)
//   EPI 2: EPI1 + Out32 = v (fp32 c) + closs += 0.1*sum(v)         (c4)
//   EPI 3: OutB = bf16(X32 - acc)                                  (r intermediate)
//   EPI 4: Out32 = acc                                             (xp)
// Epilogue: 32-row x 128-col fp32 LDS bounce chunks -> fully coalesced
// vectorized global I/O (same-thread read-before-write on aliased OutB/Cpre).
// ---------------------------------------------------------------------------
template<int EPI>
__global__ __launch_bounds__(256)
void gemm_bt(const short* __restrict__ A, const short* __restrict__ B,
             int K, int Nn,
             const unsigned short* Cc, const unsigned short* Cpre,
             const float* __restrict__ X32,
             unsigned short* OutB, float* Out32,
             float cfA, float cfB, float* loss)
{
    // union: staging (2 x 8 KB bf16) during K-loop; 32x132 fp32 bounce after
    __shared__ __align__(16) unsigned char smem[32 * 132 * 4];  // 16896 B
    short* As = (short*)smem;
    short* Bs = (short*)smem + 4096;
    float (*L)[132] = (float (*)[132])smem;
    __shared__ float red2[4];

    const int tid  = threadIdx.x;
    const int wave = tid >> 6;
    const int lane = tid & 63;
    const int rowBase = blockIdx.y * 128;
    const int colBase = blockIdx.x * 128;

    // staging map: 16 rows x 32 k per instr; lane L -> row L/4, k-chunk (L%4)*8
    const int sRow = lane >> 2;
    const int sK   = (lane & 3) << 3;
    const short* gA = A + (size_t)(rowBase + wave * 32 + sRow) * K + sK;
    const short* gB = B + (size_t)(colBase + wave * 32 + sRow) * K + sK;
    short* lA0 = &As[(wave * 32) * 32];
    short* lA1 = &As[(wave * 32 + 16) * 32];
    short* lB0 = &Bs[(wave * 32) * 32];
    short* lB1 = &Bs[(wave * 32 + 16) * 32];
    const size_t rstep = (size_t)16 * K;

    const int m16  = lane & 15;
    const int quad = lane >> 4;
    const short* paBase = &As[((wave & 1) * 64 + m16) * 32 + quad * 8];
    const short* pbBase = &Bs[((wave >> 1) * 64 + m16) * 32 + quad * 8];

    f32x4 acc[4][4] = {};

    for (int kb = 0; kb < K; kb += 32) {
        __syncthreads();                       // prev iter's ds_reads done
        async16(gA + kb,         lA0);
        async16(gA + kb + rstep, lA1);
        async16(gB + kb,         lB0);
        async16(gB + kb + rstep, lB1);
        __syncthreads();                       // drains vmcnt before barrier
        bf16x8 af[4], bfr[4];
        #pragma unroll
        for (int i = 0; i < 4; ++i) af[i]  = *(const bf16x8*)(paBase + i * 512);
        #pragma unroll
        for (int j = 0; j < 4; ++j) bfr[j] = *(const bf16x8*)(pbBase + j * 512);
        #pragma unroll
        for (int i = 0; i < 4; ++i)
            #pragma unroll
            for (int j = 0; j < 4; ++j)
                acc[i][j] = __builtin_amdgcn_mfma_f32_16x16x32_bf16(
                                af[i], bfr[j], acc[i][j], 0, 0, 0);
    }

    // ---- LDS-bounce epilogue ----
    // C/D layout: row = (wave&1)*64 + i*16 + quad*4 + reg; col = (wave>>1)*64 + j*16 + m16
    // chunk t (rows [t*32, t*32+32)): wavebit = t>>1, i-pair = t&1
    const int lrow = tid >> 3;        // 0..31
    const int seg  = tid & 7;         // 16-col segment
    float lsum = 0.f;

    #pragma unroll
    for (int t = 0; t < 4; ++t) {
        __syncthreads();              // LDS free (K-loop or prev chunk done)
        if ((wave & 1) == (t >> 1)) {
            #pragma unroll
            for (int ii = 0; ii < 2; ++ii) {
                const int i   = (t & 1) * 2 + ii;
                const int lr0 = ii * 16 + quad * 4;
                #pragma unroll
                for (int r = 0; r < 4; ++r)
                    #pragma unroll
                    for (int j = 0; j < 4; ++j)
                        L[lr0 + r][(wave >> 1) * 64 + j * 16 + m16] = acc[i][j][r];
            }
        }
        __syncthreads();

        float v[16];
        #pragma unroll
        for (int q = 0; q < 4; ++q)
            *(f32x4*)&v[q * 4] = *(const f32x4*)&L[lrow][seg * 16 + q * 4];

        const size_t gidx = (size_t)(rowBase + t * 32 + lrow) * Nn
                          + colBase + seg * 16;

        if constexpr (EPI == 0) {
            u16x8 o0, o1;
            #pragma unroll
            for (int k = 0; k < 8; ++k) {
                o0[k] = f2bf(fmaxf(S_STEP * v[k]     - LAM, 0.f));
                o1[k] = f2bf(fmaxf(S_STEP * v[k + 8] - LAM, 0.f));
            }
            *(u16x8*)(OutB + gidx)     = o0;
            *(u16x8*)(OutB + gidx + 8) = o1;
        } else if constexpr (EPI == 1 || EPI == 2) {
            const u16x8 cc0 = *(const u16x8*)(Cc   + gidx);
            const u16x8 cc1 = *(const u16x8*)(Cc   + gidx + 8);
            const u16x8 cp0 = *(const u16x8*)(Cpre + gidx);
            const u16x8 cp1 = *(const u16x8*)(Cpre + gidx + 8);
            float w[16];
            #pragma unroll
            for (int k = 0; k < 8; ++k) {
                w[k]     = fmaxf(cfA * bf2f(cc0[k]) + cfB * bf2f(cp0[k])
                                 + S_STEP * v[k]     - LAM, 0.f);
                w[k + 8] = fmaxf(cfA * bf2f(cc1[k]) + cfB * bf2f(cp1[k])
                                 + S_STEP * v[k + 8] - LAM, 0.f);
            }
            u16x8 o0, o1;
            #pragma unroll
            for (int k = 0; k < 8; ++k) { o0[k] = f2bf(w[k]); o1[k] = f2bf(w[k + 8]); }
            *(u16x8*)(OutB + gidx)     = o0;
            *(u16x8*)(OutB + gidx + 8) = o1;
            if constexpr (EPI == 2) {
                #pragma unroll
                for (int q = 0; q < 4; ++q)
                    *(f32x4*)(Out32 + gidx + q * 4) = *(const f32x4*)&w[q * 4];
                #pragma unroll
                for (int k = 0; k < 16; ++k) lsum += w[k];   // w >= 0
            }
        } else if constexpr (EPI == 3) {
            float w[16];
            #pragma unroll
            for (int q = 0; q < 4; ++q) {
                const f32x4 xv = *(const f32x4*)(X32 + gidx + q * 4);
                w[q*4+0] = xv[0] - v[q*4+0]; w[q*4+1] = xv[1] - v[q*4+1];
                w[q*4+2] = xv[2] - v[q*4+2]; w[q*4+3] = xv[3] - v[q*4+3];
            }
            u16x8 o0, o1;
            #pragma unroll
            for (int k = 0; k < 8; ++k) { o0[k] = f2bf(w[k]); o1[k] = f2bf(w[k + 8]); }
            *(u16x8*)(OutB + gidx)     = o0;
            *(u16x8*)(OutB + gidx + 8) = o1;
        } else {  // EPI 4: xp fp32
            #pragma unroll
            for (int q = 0; q < 4; ++q)
                *(f32x4*)(Out32 + gidx + q * 4) = *(const f32x4*)&v[q * 4];
        }
    }

    if constexpr (EPI == 2) {
        #pragma unroll
        for (int off = 32; off; off >>= 1) lsum += __shfl_down(lsum, off, 64);
        if (lane == 0) red2[wave] = lsum;
        __syncthreads();
        if (tid == 0)
            atomicAdd(loss, 0.1f * (red2[0] + red2[1] + red2[2] + red2[3]));
    }
}

// ---------------------------------------------------------------------------
// prep: W [2048,512] fp32 -> Wb bf16 (same layout) + Wtb bf16 [512,2048]
// ---------------------------------------------------------------------------
__global__ __launch_bounds__(256)
void cvt_w_k(const float* __restrict__ W,
             unsigned short* __restrict__ Wb, unsigned short* __restrict__ Wtb)
{
    __shared__ unsigned short T[64][65];
    const int dBase = blockIdx.y * 64;
    const int cBase = blockIdx.x * 64;
    const int lc = threadIdx.x & 63;
    const int lr = threadIdx.x >> 6;
    #pragma unroll
    for (int p = 0; p < 16; ++p) {
        const int dl = p * 4 + lr;
        const size_t idx = (size_t)(dBase + dl) * 512 + cBase + lc;
        const unsigned short b = f2bf(W[idx]);
        Wb[idx] = b;
        T[dl][lc] = b;
    }
    __syncthreads();
    #pragma unroll
    for (int p = 0; p < 16; ++p) {
        const int cl = p * 4 + lr;
        Wtb[(size_t)(cBase + cl) * 2048 + dBase + lc] = T[lc][cl];
    }
}

__global__ __launch_bounds__(256)
void cvt_x_k(const float4* __restrict__ x4, ushort4* __restrict__ xb4, int n4)
{
    for (int i = blockIdx.x * 256 + threadIdx.x; i < n4; i += gridDim.x * 256) {
        const float4 v = x4[i];
        xb4[i] = make_ushort4(f2bf(v.x), f2bf(v.y), f2bf(v.z), f2bf(v.w));
    }
}

// r = x - xp (fp32), rloss += sum(r*r)
__global__ __launch_bounds__(256)
void finalize_k(const float4* __restrict__ x4, const float4* __restrict__ xp4,
                float4* __restrict__ r4, float* __restrict__ rloss, int n4)
{
    float lsum = 0.f;
    for (int i = blockIdx.x * 256 + threadIdx.x; i < n4; i += gridDim.x * 256) {
        const float4 xv = x4[i], pv = xp4[i];
        float4 rv;
        rv.x = xv.x - pv.x; rv.y = xv.y - pv.y;
        rv.z = xv.z - pv.z; rv.w = xv.w - pv.w;
        r4[i] = rv;
        lsum += rv.x * rv.x + rv.y * rv.y + rv.z * rv.z + rv.w * rv.w;
    }
    #pragma unroll
    for (int off = 32; off; off >>= 1) lsum += __shfl_down(lsum, off, 64);
    if ((threadIdx.x & 63) == 0) atomicAdd(rloss, lsum);
}

// ---------------------------------------------------------------------------
extern "C" void kernel_launch(void* const* d_in, const int* in_sizes, int n_in,
                              void* d_out, int out_size, void* d_ws, size_t ws_size,
                              hipStream_t stream)
{
    (void)in_sizes; (void)n_in; (void)out_size; (void)ws_size;

    constexpr int N = 16384, C = 512, D = 2048;
    constexpr size_t ND = (size_t)N * D;
    constexpr size_t NC = (size_t)N * C;

    const float* x = (const float*)d_in[0];   // [N, C]
    const float* W = (const float*)d_in[1];   // [D, C]

    float* out    = (float*)d_out;
    float* c_out  = out;                      // c  [N, D] fp32
    float* xp_out = out + ND;                 // xp [N, C] fp32
    float* r_out  = out + ND + NC;            // r  [N, C] fp32
    float* rloss  = out + ND + 2 * NC;
    float* closs  = rloss + 1;

    // ws: two bf16 c generations (64 MiB each)
    short* cb0 = (short*)d_ws;
    short* cb1 = cb0 + ND;

    // scratch in dead phases of d_out (see round-2 layout notes)
    unsigned short* rb  = (unsigned short*)xp_out;            // [N,C] bf16
    unsigned short* Wb  = (unsigned short*)xp_out + NC;       // [D,C] bf16
    unsigned short* Wtb = (unsigned short*)r_out;             // [C,D] bf16
    unsigned short* xb  = (unsigned short*)r_out + (size_t)D * C;  // [N,C] bf16

    hipMemsetAsync((void*)rloss, 0, 2 * sizeof(float), stream);

    double tp = (std::sqrt(5.0) + 1.0) / 2.0;
    float cfA[5] = {0.f, 1.f, 0.f, 0.f, 0.f};
    float cfB[5] = {0.f, 0.f, 0.f, 0.f, 0.f};
    for (int i = 2; i < 5; ++i) {
        double t = (std::sqrt(1.0 + 4.0 * tp * tp) + 1.0) / 2.0;
        cfA[i] = (float)((tp + t - 1.0) / t);
        cfB[i] = (float)((1.0 - tp) / t);
        tp = t;
    }

    const dim3 blk(256);
    cvt_w_k<<<dim3(C / 64, D / 64), blk, 0, stream>>>(W, Wb, Wtb);
    cvt_x_k<<<dim3(1024), blk, 0, stream>>>((const float4*)x, (ushort4*)xb,
                                            (int)(NC / 4));

    const dim3 gridD(D / 128, N / 128);   // 16 x 128
    const dim3 gridC(C / 128, N / 128);   //  4 x 128

    // c0 = relu(S*(x@W^T) - LAM)
    gemm_bt<0><<<gridD, blk, 0, stream>>>((const short*)xb, (const short*)Wb,
                                          C, D, nullptr, nullptr, nullptr,
                                          (unsigned short*)cb0, nullptr,
                                          0.f, 0.f, nullptr);

    short* bufs[2] = {cb0, cb1};
    for (int i = 1; i < 5; ++i) {
        const short* cprev = bufs[(i - 1) & 1];   // c_{i-1}
        short*       cnew  = bufs[i & 1];         // c_{i-2} -> c_i (in place)
        const unsigned short* cpre2 =
            (i == 1) ? (const unsigned short*)cprev : (const unsigned short*)cnew;
        // r_{i-1} = x - c_{i-1} @ W   (bf16, via Wt)
        gemm_bt<3><<<gridC, blk, 0, stream>>>(cprev, (const short*)Wtb,
                                              D, C, nullptr, nullptr, x,
                                              rb, nullptr, 0.f, 0.f, nullptr);
        // c_i = relu(cfA*c_{i-1} + cfB*c_{i-2} + S*(r@W^T) - LAM)
        if (i < 4)
            gemm_bt<1><<<gridD, blk, 0, stream>>>((const short*)rb, (const short*)Wb,
                                                  C, D, (const unsigned short*)cprev,
                                                  cpre2, nullptr,
                                                  (unsigned short*)cnew, nullptr,
                                                  cfA[i], cfB[i], nullptr);
        else
            gemm_bt<2><<<gridD, blk, 0, stream>>>((const short*)rb, (const short*)Wb,
                                                  C, D, (const unsigned short*)cprev,
                                                  cpre2, nullptr,
                                                  (unsigned short*)cnew, c_out,
                                                  cfA[i], cfB[i], closs);
    }

    // xp = c4 @ W (fp32 out; overwrites rb/Wb, now dead)
    gemm_bt<4><<<gridC, blk, 0, stream>>>(cb0, (const short*)Wtb,
                                          D, C, nullptr, nullptr, nullptr,
                                          nullptr, xp_out, 0.f, 0.f, nullptr);

    // r = x - xp, rloss = sum(r*r) (overwrites Wtb/xb, now dead)
    finalize_k<<<dim3(1024), blk, 0, stream>>>((const float4*)x,
                                               (const float4*)xp_out,
                                               (float4*)r_out, rloss,
                                               (int)(NC / 4));
}

// Round 4
// 832.740 us; speedup vs baseline: 5.0174x; 1.0980x over previous
//
#include <hip/hip_runtime.h>
#include <cmath>

// FISTA sparse coding, bf16-MFMA, double-buffered K-loop (round 4).
// N=16384, C=512, D=2048, 5 steps. 10 GEMMs, 128x128 tile, 16x16x32 bf16 MFMA.
// K-loop: 2 LDS buffers, ONE barrier/iter, next iter's global_load_lds issued
// right after the barrier so it overlaps current iter's MFMAs.

typedef __attribute__((ext_vector_type(8))) short bf16x8;          // 4 VGPRs
typedef __attribute__((ext_vector_type(8))) unsigned short u16x8;  // 16 B
typedef __attribute__((ext_vector_type(4))) float f32x4;

constexpr float S_STEP = 0.1f;   // step size
constexpr float LAM    = 0.01f;  // lmbd * step (mu=0 -> s_mu=1)

__device__ __forceinline__ unsigned short f2bf(float f) {   // RNE fp32->bf16
    unsigned u = __float_as_uint(f);
    u += 0x7FFFu + ((u >> 16) & 1u);
    return (unsigned short)(u >> 16);
}
__device__ __forceinline__ float bf2f(unsigned short s) {
    return __uint_as_float(((unsigned)s) << 16);
}

__device__ __forceinline__ void async16(const void* g, void* l) {
    __builtin_amdgcn_global_load_lds(
        (const __attribute__((address_space(1))) void*)g,
        (__attribute__((address_space(3))) void*)l, 16, 0, 0);
}

// ---------------------------------------------------------------------------
// gemm_bt<EPI>: acc[m,n] = sum_k A[m,k]*B[n,k]; A:[M,K] bf16 rm, B:[Nn,K] bf16 rm.
//   EPI 0: OutB = bf16(relu(S*acc - LAM))                          (c0)
//   EPI 1: OutB = bf16(relu(cfA*Cc + cfB*Cpre + S*acc - LAM))      (c1..c3)
//   EPI 2: EPI1 + Out32 = v (fp32 c) + closs += 0.1*sum(v)         (c4)
//   EPI 3: OutB = bf16(Xb - acc)   (r intermediate, bf16 x read)
//   EPI 4: Out32 = acc                                             (xp)
// ---------------------------------------------------------------------------
template<int EPI>
__global__ __launch_bounds__(256)
void gemm_bt(const short* __restrict__ A, const short* __restrict__ B,
             int K, int Nn,
             const unsigned short* Cc, const unsigned short* Cpre,
             const unsigned short* __restrict__ Xb,
             unsigned short* OutB, float* Out32,
             float cfA, float cfB, float* loss)
{
    // 32 KB: K-loop = 2 x (8KB A + 8KB B); epilogue = 32x132 fp32 bounce
    __shared__ __align__(16) unsigned char smem[32768];
    short* S  = (short*)smem;                 // buffers: A(b)=b*4096, B(b)=8192+b*4096
    float (*L)[132] = (float (*)[132])smem;   // bounce uses first 16896 B
    float* red2 = (float*)(smem + 32736);     // after bounce region, K-loop done

    const int tid  = threadIdx.x;
    const int wave = tid >> 6;
    const int lane = tid & 63;
    const int rowBase = blockIdx.y * 128;
    const int colBase = blockIdx.x * 128;

    // staging map: 16 rows x 32 k per instr; lane L -> row L/4, k-chunk (L%4)*8
    const int sRow = lane >> 2;
    const int sK   = (lane & 3) << 3;
    const short* gA = A + (size_t)(rowBase + wave * 32 + sRow) * K + sK;
    const short* gB = B + (size_t)(colBase + wave * 32 + sRow) * K + sK;
    const size_t rstep = (size_t)16 * K;
    short* lA = S + (wave * 32) * 32;         // + b*4096
    short* lB = S + 8192 + (wave * 32) * 32;  // + b*4096

    const int m16  = lane & 15;
    const int quad = lane >> 4;
    const short* paBase = S + ((wave & 1) * 64 + m16) * 32 + quad * 8;
    const short* pbBase = S + 8192 + ((wave >> 1) * 64 + m16) * 32 + quad * 8;

    f32x4 acc[4][4] = {};
    const int nIter = K >> 5;

    // prologue: stage iter 0 into buffer 0
    {
        async16(gA,         lA);
        async16(gA + rstep, lA + 512);
        async16(gB,         lB);
        async16(gB + rstep, lB + 512);
    }

    for (int it = 0; it < nIter; ++it) {
        __syncthreads();   // vmcnt(0) drain: buf[it&1] staged; prev reads done
        if (it + 1 < nIter) {
            const int nb = (it + 1) & 1;
            const int kb = (it + 1) << 5;
            async16(gA + kb,         lA + nb * 4096);
            async16(gA + kb + rstep, lA + nb * 4096 + 512);
            async16(gB + kb,         lB + nb * 4096);
            async16(gB + kb + rstep, lB + nb * 4096 + 512);
        }
        const int cb = (it & 1) * 4096;
        bf16x8 af[4], bfr[4];
        #pragma unroll
        for (int i = 0; i < 4; ++i) af[i]  = *(const bf16x8*)(paBase + cb + i * 512);
        #pragma unroll
        for (int j = 0; j < 4; ++j) bfr[j] = *(const bf16x8*)(pbBase + cb + j * 512);
        #pragma unroll
        for (int i = 0; i < 4; ++i)
            #pragma unroll
            for (int j = 0; j < 4; ++j)
                acc[i][j] = __builtin_amdgcn_mfma_f32_16x16x32_bf16(
                                af[i], bfr[j], acc[i][j], 0, 0, 0);
    }

    // ---- LDS-bounce epilogue (coalesced global I/O) ----
    // C/D layout: row = (wave&1)*64 + i*16 + quad*4 + reg; col = (wave>>1)*64 + j*16 + m16
    const int lrow = tid >> 3;        // 0..31
    const int seg  = tid & 7;         // 16-col segment
    float lsum = 0.f;

    #pragma unroll
    for (int t = 0; t < 4; ++t) {
        __syncthreads();              // LDS free (K-loop or prev chunk done)
        if ((wave & 1) == (t >> 1)) {
            #pragma unroll
            for (int ii = 0; ii < 2; ++ii) {
                const int i   = (t & 1) * 2 + ii;
                const int lr0 = ii * 16 + quad * 4;
                #pragma unroll
                for (int r = 0; r < 4; ++r)
                    #pragma unroll
                    for (int j = 0; j < 4; ++j)
                        L[lr0 + r][(wave >> 1) * 64 + j * 16 + m16] = acc[i][j][r];
            }
        }
        __syncthreads();

        float v[16];
        #pragma unroll
        for (int q = 0; q < 4; ++q)
            *(f32x4*)&v[q * 4] = *(const f32x4*)&L[lrow][seg * 16 + q * 4];

        const size_t gidx = (size_t)(rowBase + t * 32 + lrow) * Nn
                          + colBase + seg * 16;

        if constexpr (EPI == 0) {
            u16x8 o0, o1;
            #pragma unroll
            for (int k = 0; k < 8; ++k) {
                o0[k] = f2bf(fmaxf(S_STEP * v[k]     - LAM, 0.f));
                o1[k] = f2bf(fmaxf(S_STEP * v[k + 8] - LAM, 0.f));
            }
            *(u16x8*)(OutB + gidx)     = o0;
            *(u16x8*)(OutB + gidx + 8) = o1;
        } else if constexpr (EPI == 1 || EPI == 2) {
            const u16x8 cc0 = *(const u16x8*)(Cc   + gidx);
            const u16x8 cc1 = *(const u16x8*)(Cc   + gidx + 8);
            const u16x8 cp0 = *(const u16x8*)(Cpre + gidx);
            const u16x8 cp1 = *(const u16x8*)(Cpre + gidx + 8);
            float w[16];
            #pragma unroll
            for (int k = 0; k < 8; ++k) {
                w[k]     = fmaxf(cfA * bf2f(cc0[k]) + cfB * bf2f(cp0[k])
                                 + S_STEP * v[k]     - LAM, 0.f);
                w[k + 8] = fmaxf(cfA * bf2f(cc1[k]) + cfB * bf2f(cp1[k])
                                 + S_STEP * v[k + 8] - LAM, 0.f);
            }
            u16x8 o0, o1;
            #pragma unroll
            for (int k = 0; k < 8; ++k) { o0[k] = f2bf(w[k]); o1[k] = f2bf(w[k + 8]); }
            *(u16x8*)(OutB + gidx)     = o0;
            *(u16x8*)(OutB + gidx + 8) = o1;
            if constexpr (EPI == 2) {
                #pragma unroll
                for (int q = 0; q < 4; ++q)
                    *(f32x4*)(Out32 + gidx + q * 4) = *(const f32x4*)&w[q * 4];
                #pragma unroll
                for (int k = 0; k < 16; ++k) lsum += w[k];   // w >= 0
            }
        } else if constexpr (EPI == 3) {
            const u16x8 xb0 = *(const u16x8*)(Xb + gidx);
            const u16x8 xb1 = *(const u16x8*)(Xb + gidx + 8);
            u16x8 o0, o1;
            #pragma unroll
            for (int k = 0; k < 8; ++k) {
                o0[k] = f2bf(bf2f(xb0[k]) - v[k]);
                o1[k] = f2bf(bf2f(xb1[k]) - v[k + 8]);
            }
            *(u16x8*)(OutB + gidx)     = o0;
            *(u16x8*)(OutB + gidx + 8) = o1;
        } else {  // EPI 4: xp fp32
            #pragma unroll
            for (int q = 0; q < 4; ++q)
                *(f32x4*)(Out32 + gidx + q * 4) = *(const f32x4*)&v[q * 4];
        }
    }

    if constexpr (EPI == 2) {
        #pragma unroll
        for (int off = 32; off; off >>= 1) lsum += __shfl_down(lsum, off, 64);
        if (lane == 0) red2[wave] = lsum;
        __syncthreads();
        if (tid == 0)
            atomicAdd(loss, 0.1f * (red2[0] + red2[1] + red2[2] + red2[3]));
    }
}

// ---------------------------------------------------------------------------
// prep: W [2048,512] fp32 -> Wb bf16 (same layout) + Wtb bf16 [512,2048]
// ---------------------------------------------------------------------------
__global__ __launch_bounds__(256)
void cvt_w_k(const float* __restrict__ W,
             unsigned short* __restrict__ Wb, unsigned short* __restrict__ Wtb)
{
    __shared__ unsigned short T[64][65];
    const int dBase = blockIdx.y * 64;
    const int cBase = blockIdx.x * 64;
    const int lc = threadIdx.x & 63;
    const int lr = threadIdx.x >> 6;
    #pragma unroll
    for (int p = 0; p < 16; ++p) {
        const int dl = p * 4 + lr;
        const size_t idx = (size_t)(dBase + dl) * 512 + cBase + lc;
        const unsigned short b = f2bf(W[idx]);
        Wb[idx] = b;
        T[dl][lc] = b;
    }
    __syncthreads();
    #pragma unroll
    for (int p = 0; p < 16; ++p) {
        const int cl = p * 4 + lr;
        Wtb[(size_t)(cBase + cl) * 2048 + dBase + lc] = T[lc][cl];
    }
}

__global__ __launch_bounds__(256)
void cvt_x_k(const float4* __restrict__ x4, ushort4* __restrict__ xb4, int n4)
{
    for (int i = blockIdx.x * 256 + threadIdx.x; i < n4; i += gridDim.x * 256) {
        const float4 v = x4[i];
        xb4[i] = make_ushort4(f2bf(v.x), f2bf(v.y), f2bf(v.z), f2bf(v.w));
    }
}

// r = x - xp (fp32), rloss += sum(r*r)
__global__ __launch_bounds__(256)
void finalize_k(const float4* __restrict__ x4, const float4* __restrict__ xp4,
                float4* __restrict__ r4, float* __restrict__ rloss, int n4)
{
    float lsum = 0.f;
    for (int i = blockIdx.x * 256 + threadIdx.x; i < n4; i += gridDim.x * 256) {
        const float4 xv = x4[i], pv = xp4[i];
        float4 rv;
        rv.x = xv.x - pv.x; rv.y = xv.y - pv.y;
        rv.z = xv.z - pv.z; rv.w = xv.w - pv.w;
        r4[i] = rv;
        lsum += rv.x * rv.x + rv.y * rv.y + rv.z * rv.z + rv.w * rv.w;
    }
    #pragma unroll
    for (int off = 32; off; off >>= 1) lsum += __shfl_down(lsum, off, 64);
    if ((threadIdx.x & 63) == 0) atomicAdd(rloss, lsum);
}

// ---------------------------------------------------------------------------
extern "C" void kernel_launch(void* const* d_in, const int* in_sizes, int n_in,
                              void* d_out, int out_size, void* d_ws, size_t ws_size,
                              hipStream_t stream)
{
    (void)in_sizes; (void)n_in; (void)out_size; (void)ws_size;

    constexpr int N = 16384, C = 512, D = 2048;
    constexpr size_t ND = (size_t)N * D;
    constexpr size_t NC = (size_t)N * C;

    const float* x = (const float*)d_in[0];   // [N, C]
    const float* W = (const float*)d_in[1];   // [D, C]

    float* out    = (float*)d_out;
    float* c_out  = out;                      // c  [N, D] fp32
    float* xp_out = out + ND;                 // xp [N, C] fp32
    float* r_out  = out + ND + NC;            // r  [N, C] fp32
    float* rloss  = out + ND + 2 * NC;
    float* closs  = rloss + 1;

    // ws: two bf16 c generations (64 MiB each)
    short* cb0 = (short*)d_ws;
    short* cb1 = cb0 + ND;

    // scratch in dead phases of d_out:
    // xp region: rb (16MB) + Wb (2MB)  — dead before final xp write
    // r  region: Wtb (2MB) + xb (16MB) — dead before finalize_k overwrite
    unsigned short* rb  = (unsigned short*)xp_out;            // [N,C] bf16
    unsigned short* Wb  = (unsigned short*)xp_out + NC;       // [D,C] bf16
    unsigned short* Wtb = (unsigned short*)r_out;             // [C,D] bf16
    unsigned short* xb  = (unsigned short*)r_out + (size_t)D * C;  // [N,C] bf16

    hipMemsetAsync((void*)rloss, 0, 2 * sizeof(float), stream);

    double tp = (std::sqrt(5.0) + 1.0) / 2.0;
    float cfA[5] = {0.f, 1.f, 0.f, 0.f, 0.f};
    float cfB[5] = {0.f, 0.f, 0.f, 0.f, 0.f};
    for (int i = 2; i < 5; ++i) {
        double t = (std::sqrt(1.0 + 4.0 * tp * tp) + 1.0) / 2.0;
        cfA[i] = (float)((tp + t - 1.0) / t);
        cfB[i] = (float)((1.0 - tp) / t);
        tp = t;
    }

    const dim3 blk(256);
    cvt_w_k<<<dim3(C / 64, D / 64), blk, 0, stream>>>(W, Wb, Wtb);
    cvt_x_k<<<dim3(1024), blk, 0, stream>>>((const float4*)x, (ushort4*)xb,
                                            (int)(NC / 4));

    const dim3 gridD(D / 128, N / 128);   // 16 x 128
    const dim3 gridC(C / 128, N / 128);   //  4 x 128

    // c0 = relu(S*(x@W^T) - LAM)
    gemm_bt<0><<<gridD, blk, 0, stream>>>((const short*)xb, (const short*)Wb,
                                          C, D, nullptr, nullptr, nullptr,
                                          (unsigned short*)cb0, nullptr,
                                          0.f, 0.f, nullptr);

    short* bufs[2] = {cb0, cb1};
    for (int i = 1; i < 5; ++i) {
        const short* cprev = bufs[(i - 1) & 1];   // c_{i-1}
        short*       cnew  = bufs[i & 1];         // c_{i-2} -> c_i (in place)
        const unsigned short* cpre2 =
            (i == 1) ? (const unsigned short*)cprev : (const unsigned short*)cnew;
        // r_{i-1} = x - c_{i-1} @ W   (bf16, via Wt; reads xb)
        gemm_bt<3><<<gridC, blk, 0, stream>>>(cprev, (const short*)Wtb,
                                              D, C, nullptr, nullptr, xb,
                                              rb, nullptr, 0.f, 0.f, nullptr);
        // c_i = relu(cfA*c_{i-1} + cfB*c_{i-2} + S*(r@W^T) - LAM)
        if (i < 4)
            gemm_bt<1><<<gridD, blk, 0, stream>>>((const short*)rb, (const short*)Wb,
                                                  C, D, (const unsigned short*)cprev,
                                                  cpre2, nullptr,
                                                  (unsigned short*)cnew, nullptr,
                                                  cfA[i], cfB[i], nullptr);
        else
            gemm_bt<2><<<gridD, blk, 0, stream>>>((const short*)rb, (const short*)Wb,
                                                  C, D, (const unsigned short*)cprev,
                                                  cpre2, nullptr,
                                                  (unsigned short*)cnew, c_out,
                                                  cfA[i], cfB[i], closs);
    }

    // xp = c4 @ W (fp32 out; overwrites rb/Wb, now dead)
    gemm_bt<4><<<gridC, blk, 0, stream>>>(cb0, (const short*)Wtb,
                                          D, C, nullptr, nullptr, nullptr,
                                          nullptr, xp_out, 0.f, 0.f, nullptr);

    // r = x - xp, rloss = sum(r*r) (overwrites Wtb/xb, now dead)
    finalize_k<<<dim3(1024), blk, 0, stream>>>((const float4*)x,
                                               (const float4*)xp_out,
                                               (float4*)r_out, rloss,
                                               (int)(NC / 4));
}